// Round 5
// baseline (51.963 us; speedup 1.0000x reference)
//
#include <hip/hip_runtime.h>

// SplineDisp: field[v] = ma @ (g(v) + cubic_bspline_pull(coeff, g(v))),
// g(v) = fa @ v, fa = inv(affine)@fix_affine, ma = inv(mov_affine)@affine.
// Fixed size: coeff [80,80,80,3] f32, out [160,160,160,3] f32.
// R5: separable 3-pass; per-axis tap TABLES (float4 weights + int4 pre-wrapped
// offsets, built once in setup) replace per-thread floor/poly/wrap work; all
// three passes coarsened 8x along their filter axis with a 4-deep register
// sliding window (grid stride per axis uniform in (0,1] -> floor advances
// by 0 or 1 per output).
//
// d_ws layout: [0,256)   M: fa(16), ma(16), flag(1)
//              [256, +7680)    W tables: axis x,y,z each 160 float4
//              [8192? no..]    (W at 256, O at 256+7680, 160*16 each)
//              [32768, +16.4M) T1  [x][y][k] float4
//              [~16.4M, +32.8M) T2 [x][j][k] float4

#define CX 80
#define FD 160
#define TBL_W_OFF 256
#define TBL_O_OFF (256 + 3*160*16)
#define T1_OFF 32768

__device__ inline void inv4(const float* m, float* inv) {
    inv[0]  =  m[5]*m[10]*m[15] - m[5]*m[11]*m[14] - m[9]*m[6]*m[15] + m[9]*m[7]*m[14] + m[13]*m[6]*m[11] - m[13]*m[7]*m[10];
    inv[4]  = -m[4]*m[10]*m[15] + m[4]*m[11]*m[14] + m[8]*m[6]*m[15] - m[8]*m[7]*m[14] - m[12]*m[6]*m[11] + m[12]*m[7]*m[10];
    inv[8]  =  m[4]*m[9]*m[15]  - m[4]*m[11]*m[13] - m[8]*m[5]*m[15] + m[8]*m[7]*m[13] + m[12]*m[5]*m[11] - m[12]*m[7]*m[9];
    inv[12] = -m[4]*m[9]*m[14]  + m[4]*m[10]*m[13] + m[8]*m[5]*m[14] - m[8]*m[6]*m[13] - m[12]*m[5]*m[10] + m[12]*m[6]*m[9];
    inv[1]  = -m[1]*m[10]*m[15] + m[1]*m[11]*m[14] + m[9]*m[2]*m[15] - m[9]*m[3]*m[14] - m[13]*m[2]*m[11] + m[13]*m[3]*m[10];
    inv[5]  =  m[0]*m[10]*m[15] - m[0]*m[11]*m[14] - m[8]*m[2]*m[15] + m[8]*m[3]*m[14] + m[12]*m[2]*m[11] - m[12]*m[3]*m[10];
    inv[9]  = -m[0]*m[9]*m[15]  + m[0]*m[11]*m[13] + m[8]*m[1]*m[15] - m[8]*m[3]*m[13] - m[12]*m[1]*m[11] + m[12]*m[3]*m[9];
    inv[13] =  m[0]*m[9]*m[14]  - m[0]*m[10]*m[13] - m[8]*m[1]*m[14] + m[8]*m[2]*m[13] + m[12]*m[1]*m[10] - m[12]*m[2]*m[9];
    inv[2]  =  m[1]*m[6]*m[15]  - m[1]*m[7]*m[14]  - m[5]*m[2]*m[15] + m[5]*m[3]*m[14] + m[13]*m[2]*m[7]  - m[13]*m[3]*m[6];
    inv[6]  = -m[0]*m[6]*m[15]  + m[0]*m[7]*m[14]  + m[4]*m[2]*m[15] - m[4]*m[3]*m[14] - m[12]*m[2]*m[7]  + m[12]*m[3]*m[6];
    inv[10] =  m[0]*m[5]*m[15]  - m[0]*m[7]*m[13]  - m[4]*m[1]*m[15] + m[4]*m[3]*m[13] + m[12]*m[1]*m[7]  - m[12]*m[3]*m[5];
    inv[14] = -m[0]*m[5]*m[14]  + m[0]*m[6]*m[13]  + m[4]*m[1]*m[14] - m[4]*m[2]*m[13] - m[12]*m[1]*m[6]  + m[12]*m[2]*m[5];
    inv[3]  = -m[1]*m[6]*m[11]  + m[1]*m[7]*m[10]  + m[5]*m[2]*m[11] - m[5]*m[3]*m[10] - m[9]*m[2]*m[7]   + m[9]*m[3]*m[6];
    inv[7]  =  m[0]*m[6]*m[11]  - m[0]*m[7]*m[10]  - m[4]*m[2]*m[11] + m[4]*m[3]*m[10] + m[8]*m[2]*m[7]   - m[8]*m[3]*m[6];
    inv[11] = -m[0]*m[5]*m[11]  + m[0]*m[7]*m[9]   + m[4]*m[1]*m[11] - m[4]*m[3]*m[9]  - m[8]*m[1]*m[7]   + m[8]*m[3]*m[5];
    inv[15] =  m[0]*m[5]*m[10]  - m[0]*m[6]*m[9]   - m[4]*m[1]*m[10] + m[4]*m[2]*m[9]  + m[8]*m[1]*m[6]   - m[8]*m[2]*m[5];
    float det = m[0]*inv[0] + m[1]*inv[4] + m[2]*inv[8] + m[3]*inv[12];
    float rdet = 1.0f / det;
    for (int i = 0; i < 16; ++i) inv[i] *= rdet;
}

__device__ inline void bspline_w(float t, float w[4]) {
    float t2 = t * t;
    float t3 = t2 * t;
    const float s = 1.0f / 6.0f;
    w[0] = (1.f - 3.f*t + 3.f*t2 - t3) * s;
    w[1] = (4.f - 6.f*t2 + 3.f*t3) * s;
    w[2] = (1.f + 3.f*t + 3.f*t2 - 3.f*t3) * s;
    w[3] = t3 * s;
}

__device__ inline int wrap80(int v) {
    int r = v % CX;
    return (r < 0) ? r + CX : r;
}

// One block, 512 threads. Thread 0 writes M; threads 0..479 build tap tables
// (axis 0 = x offsets in T2 float4 elems, 1 = y in T1 float4 elems,
//  2 = z in coeff float elems). Tables only written when do_tables != 0.
__global__ void setup_all(const float* __restrict__ affine,
                          const float* __restrict__ fix_aff,
                          const float* __restrict__ mov_aff,
                          float* __restrict__ M, int do_tables) {
    int t = threadIdx.x;
    float invA[16], invM[16], fa[16];
    inv4(affine, invA);
    inv4(mov_aff, invM);
    for (int r = 0; r < 4; ++r)
        for (int c = 0; c < 4; ++c) {
            float s = 0.f;
            for (int k = 0; k < 4; ++k) s += invA[r*4+k] * fix_aff[k*4+c];
            fa[r*4+c] = s;
        }
    if (t == 0) {
        for (int q = 0; q < 16; ++q) M[q] = fa[q];
        for (int r = 0; r < 4; ++r)
            for (int c = 0; c < 4; ++c) {
                float s = 0.f;
                for (int k = 0; k < 4; ++k) s += invM[r*4+k] * affine[k*4+c];
                M[16 + r*4+c] = s;
            }
        float od = fabsf(fa[1]) + fabsf(fa[2]) + fabsf(fa[4]) + fabsf(fa[6]) + fabsf(fa[8]) + fabsf(fa[9]);
        int ok = (od < 1e-20f)
              && (fa[0]  > 0.f) && (fa[0]  <= 1.f)
              && (fa[5]  > 0.f) && (fa[5]  <= 1.f)
              && (fa[10] > 0.f) && (fa[10] <= 1.f);
        M[32] = ok ? 1.f : 0.f;
    }
    if (do_tables && t < 480) {
        int axis = t / 160;          // 0:x 1:y 2:z
        int idx = t % 160;
        float scale = fa[axis*4 + axis];
        float off   = fa[axis*4 + 3];
        float g = scale * (float)idx + off;
        float fg = floorf(g);
        float w[4];
        bspline_w(g - fg, w);
        int b = (int)fg - 1;
        int stride = (axis == 0) ? FD*FD : (axis == 1) ? FD : 3;
        int4 o;
        o.x = wrap80(b)     * stride;
        o.y = wrap80(b + 1) * stride;
        o.z = wrap80(b + 2) * stride;
        o.w = wrap80(b + 3) * stride;
        float4* W = (float4*)((char*)M + TBL_W_OFF) + axis*160;
        int4*   O = (int4*)  ((char*)M + TBL_O_OFF) + axis*160;
        float4 wv; wv.x = w[0]; wv.y = w[1]; wv.z = w[2]; wv.w = w[3];
        W[idx] = wv;
        O[idx] = o;
    }
}

// Pass 1: z-interp, coarsened 8 k's/thread with sliding window over z taps.
// T1[x][y][k] = sum_c wz[k][c]*coeff[x][y][zc]. 80*80*20 = 128,000 threads.
__global__ __launch_bounds__(256) void pass_z_c(const float* __restrict__ coeff,
                                                const float* __restrict__ M,
                                                float4* __restrict__ T1) {
    if (M[32] == 0.f) return;
    int tid = blockIdx.x * 256 + threadIdx.x;
    int kg = tid % 20;
    int r  = tid / 20;              // x*80 + y
    int k0 = kg * 8;

    const float4* WZ = (const float4*)((const char*)M + TBL_W_OFF) + 2*160;
    const int4*   OZ = (const int4*)  ((const char*)M + TBL_O_OFF) + 2*160;
    const float* base = coeff + (size_t)r * (CX*3);

    int4 o = OZ[k0];
    int prev = o.x;
    float w00 = base[o.x], w01 = base[o.x+1], w02 = base[o.x+2];
    float w10 = base[o.y], w11 = base[o.y+1], w12 = base[o.y+2];
    float w20 = base[o.z], w21 = base[o.z+1], w22 = base[o.z+2];
    float w30 = base[o.w], w31 = base[o.w+1], w32 = base[o.w+2];

    float4* To = T1 + (size_t)r * FD + k0;
#pragma unroll
    for (int d = 0; d < 8; ++d) {
        int k = k0 + d;
        if (d > 0) {
            int4 on = OZ[k];
            if (on.x != prev) {
                w00 = w10; w01 = w11; w02 = w12;
                w10 = w20; w11 = w21; w12 = w22;
                w20 = w30; w21 = w31; w22 = w32;
                w30 = base[on.w]; w31 = base[on.w+1]; w32 = base[on.w+2];
            }
            prev = on.x;
        }
        float4 wv = WZ[k];
        float4 v;
        v.x = wv.x*w00 + wv.y*w10 + wv.z*w20 + wv.w*w30;
        v.y = wv.x*w01 + wv.y*w11 + wv.z*w21 + wv.w*w31;
        v.z = wv.x*w02 + wv.y*w12 + wv.z*w22 + wv.w*w32;
        v.w = 0.f;
        To[d] = v;
    }
}

// Pass 2: y-interp, coarsened 8 j's/thread. T2[x][j][k] = sum_b wy[j][b]*T1[x][yb][k].
// 80*20*160 = 256,000 threads; taps fully coalesced along k.
__global__ __launch_bounds__(256) void pass_y_c(const float* __restrict__ M,
                                                const float4* __restrict__ T1,
                                                float4* __restrict__ T2) {
    if (M[32] == 0.f) return;
    int tid = blockIdx.x * 256 + threadIdx.x;
    int k = tid % FD;
    int r = tid / FD;
    int jg = r % 20;
    int x = r / 20;
    int j0 = jg * 8;

    const float4* WY = (const float4*)((const char*)M + TBL_W_OFF) + 160;
    const int4*   OY = (const int4*)  ((const char*)M + TBL_O_OFF) + 160;
    const float4* Tx = T1 + (size_t)x * CX * FD + k;

    int4 o = OY[j0];
    int prev = o.x;
    float4 w0 = Tx[o.x], w1 = Tx[o.y], w2 = Tx[o.z], w3 = Tx[o.w];

    float4* To = T2 + ((size_t)(x * FD + j0)) * FD + k;
#pragma unroll
    for (int d = 0; d < 8; ++d) {
        int j = j0 + d;
        if (d > 0) {
            int4 on = OY[j];
            if (on.x != prev) {
                w0 = w1; w1 = w2; w2 = w3;
                w3 = Tx[on.w];
            }
            prev = on.x;
        }
        float4 wv = WY[j];
        float4 v;
        v.x = wv.x*w0.x + wv.y*w1.x + wv.z*w2.x + wv.w*w3.x;
        v.y = wv.x*w0.y + wv.y*w1.y + wv.z*w2.y + wv.w*w3.y;
        v.z = wv.x*w0.z + wv.y*w1.z + wv.z*w2.z + wv.w*w3.z;
        v.w = 0.f;
        To[(size_t)d * FD] = v;
    }
}

// Pass 3: x-interp + displacement + ma affine, coarsened 8 i's/thread.
// 20*160*160 = 512,000 threads.
__global__ __launch_bounds__(256) void pass_x_c(const float* __restrict__ coeff,
                                                const float* __restrict__ M,
                                                const float4* __restrict__ T2,
                                                float* __restrict__ out) {
    int tid = blockIdx.x * 256 + threadIdx.x;
    int k = tid % FD;
    int r = tid / FD;
    int j = r % FD;
    int ig = r / FD;
    int i0 = ig * 8;

    if (M[32] != 0.f) {
        const float m0 = M[0], m3 = M[3];
        const float gy = M[5] * (float)j + M[7];
        const float gz = M[10] * (float)k + M[11];
        const float4* WX = (const float4*)((const char*)M + TBL_W_OFF);
        const int4*   OX = (const int4*)  ((const char*)M + TBL_O_OFF);
        const float4* Tjk = T2 + (size_t)j * FD + k;

        int4 o = OX[i0];
        int prev = o.x;
        float4 w0 = Tjk[o.x], w1 = Tjk[o.y], w2 = Tjk[o.z], w3 = Tjk[o.w];

        float* po = out + (((size_t)(i0 * FD + j)) * FD + k) * 3;
#pragma unroll
        for (int d = 0; d < 8; ++d) {
            int i = i0 + d;
            if (d > 0) {
                int4 on = OX[i];
                if (on.x != prev) {
                    w0 = w1; w1 = w2; w2 = w3;
                    w3 = Tjk[on.w];
                }
                prev = on.x;
            }
            float4 wv = WX[i];
            float a0 = wv.x*w0.x + wv.y*w1.x + wv.z*w2.x + wv.w*w3.x;
            float a1 = wv.x*w0.y + wv.y*w1.y + wv.z*w2.y + wv.w*w3.y;
            float a2 = wv.x*w0.z + wv.y*w1.z + wv.z*w2.z + wv.w*w3.z;
            float gxd = m0 * (float)i + m3;
            float ux = gxd + a0, uy = gy + a1, uz = gz + a2;
            po[0] = M[16]*ux + M[17]*uy + M[18]*uz + M[19];
            po[1] = M[20]*ux + M[21]*uy + M[22]*uz + M[23];
            po[2] = M[24]*ux + M[25]*uy + M[26]*uz + M[27];
            po += (size_t)FD * FD * 3;
        }
    } else {
        // non-separable fallback: direct 64-tap per output
        for (int d = 0; d < 8; ++d) {
            int i = i0 + d;
            float fi = (float)i, fj = (float)j, fk = (float)k;
            float gx = M[0]*fi + M[1]*fj + M[2]*fk  + M[3];
            float gy = M[4]*fi + M[5]*fj + M[6]*fk  + M[7];
            float gz = M[8]*fi + M[9]*fj + M[10]*fk + M[11];
            float fx = floorf(gx), fy = floorf(gy), fz = floorf(gz);
            float wx[4], wy[4], wz[4];
            bspline_w(gx - fx, wx);
            bspline_w(gy - fy, wy);
            bspline_w(gz - fz, wz);
            int bxw = wrap80((int)fx - 1);
            int byw = wrap80((int)fy - 1);
            int bzw = wrap80((int)fz - 1);
            int ox[4], oy[4], oz[4];
            for (int a = 0; a < 4; ++a) {
                int xa = bxw + a; if (xa >= CX) xa -= CX;
                int ya = byw + a; if (ya >= CX) ya -= CX;
                int za = bzw + a; if (za >= CX) za -= CX;
                ox[a] = xa * (CX*CX*3);
                oy[a] = ya * (CX*3);
                oz[a] = za * 3;
            }
            float a0 = 0.f, a1 = 0.f, a2 = 0.f;
            for (int a = 0; a < 4; ++a)
                for (int b = 0; b < 4; ++b)
                    for (int c = 0; c < 4; ++c) {
                        float w = wx[a] * wy[b] * wz[c];
                        const float* p = coeff + (ox[a] + oy[b] + oz[c]);
                        a0 = fmaf(w, p[0], a0);
                        a1 = fmaf(w, p[1], a1);
                        a2 = fmaf(w, p[2], a2);
                    }
            float ux = gx + a0, uy = gy + a1, uz = gz + a2;
            size_t oo = ((size_t)(i * FD + j) * FD + k) * 3;
            out[oo + 0] = M[16]*ux + M[17]*uy + M[18]*uz + M[19];
            out[oo + 1] = M[20]*ux + M[21]*uy + M[22]*uz + M[23];
            out[oo + 2] = M[24]*ux + M[25]*uy + M[26]*uz + M[27];
        }
    }
}

// Direct path used when ws can't hold intermediates.
__global__ __launch_bounds__(256) void spline_direct(const float* __restrict__ coeff,
                                                     const float* __restrict__ M,
                                                     float* __restrict__ out) {
    int tid = blockIdx.x * 256 + threadIdx.x;
    int k = tid % FD;
    int r = tid / FD;
    int j = r % FD;
    int i = r / FD;
    float fi = (float)i, fj = (float)j, fk = (float)k;
    float gx = M[0]*fi + M[1]*fj + M[2]*fk  + M[3];
    float gy = M[4]*fi + M[5]*fj + M[6]*fk  + M[7];
    float gz = M[8]*fi + M[9]*fj + M[10]*fk + M[11];
    float fx = floorf(gx), fy = floorf(gy), fz = floorf(gz);
    float wx[4], wy[4], wz[4];
    bspline_w(gx - fx, wx);
    bspline_w(gy - fy, wy);
    bspline_w(gz - fz, wz);
    int bxw = wrap80((int)fx - 1);
    int byw = wrap80((int)fy - 1);
    int bzw = wrap80((int)fz - 1);
    int ox[4], oy[4], oz[4];
#pragma unroll
    for (int a = 0; a < 4; ++a) {
        int xa = bxw + a; if (xa >= CX) xa -= CX;
        int ya = byw + a; if (ya >= CX) ya -= CX;
        int za = bzw + a; if (za >= CX) za -= CX;
        ox[a] = xa * (CX*CX*3);
        oy[a] = ya * (CX*3);
        oz[a] = za * 3;
    }
    float a0 = 0.f, a1 = 0.f, a2 = 0.f;
#pragma unroll
    for (int a = 0; a < 4; ++a)
#pragma unroll
        for (int b = 0; b < 4; ++b)
#pragma unroll
            for (int c = 0; c < 4; ++c) {
                float w = wx[a] * wy[b] * wz[c];
                const float* p = coeff + (ox[a] + oy[b] + oz[c]);
                a0 = fmaf(w, p[0], a0);
                a1 = fmaf(w, p[1], a1);
                a2 = fmaf(w, p[2], a2);
            }
    float ux = gx + a0, uy = gy + a1, uz = gz + a2;
    out[tid*3 + 0] = M[16]*ux + M[17]*uy + M[18]*uz + M[19];
    out[tid*3 + 1] = M[20]*ux + M[21]*uy + M[22]*uz + M[23];
    out[tid*3 + 2] = M[24]*ux + M[25]*uy + M[26]*uz + M[27];
}

extern "C" void kernel_launch(void* const* d_in, const int* in_sizes, int n_in,
                              void* d_out, int out_size, void* d_ws, size_t ws_size,
                              hipStream_t stream) {
    const float* coeff   = (const float*)d_in[0];
    const float* affine  = (const float*)d_in[1];
    const float* fix_aff = (const float*)d_in[2];
    const float* mov_aff = (const float*)d_in[3];
    float* M   = (float*)d_ws;
    char*  ws  = (char*)d_ws;
    float4* T1 = (float4*)(ws + T1_OFF);                           // 16,384,000 B
    float4* T2 = (float4*)(ws + T1_OFF + (size_t)CX*CX*FD*16);     // 32,768,000 B
    float* out = (float*)d_out;

    const size_t need = T1_OFF + (size_t)CX*CX*FD*16 + (size_t)CX*FD*FD*16;
    const int big = (ws_size >= need) ? 1 : 0;

    setup_all<<<1, 512, 0, stream>>>(affine, fix_aff, mov_aff, M, big);

    if (big) {
        pass_z_c<<<(CX*CX*20)/256, 256, 0, stream>>>(coeff, M, T1);
        pass_y_c<<<(CX*20*FD)/256, 256, 0, stream>>>(M, T1, T2);
        pass_x_c<<<(20*FD*FD)/256, 256, 0, stream>>>(coeff, M, T2, out);
    } else {
        spline_direct<<<(FD*FD*FD)/256, 256, 0, stream>>>(coeff, M, out);
    }
}

// Round 6
// 51.693 us; speedup vs baseline: 1.0052x; 1.0052x over previous
//
#include <hip/hip_runtime.h>

// SplineDisp: field[v] = ma @ (g(v) + cubic_bspline_pull(coeff, g(v))),
// g(v) = fa @ v, fa = inv(affine)@fix_affine, ma = inv(mov_affine)@affine.
// Fixed size: coeff [80,80,80,3] f32, out [160,160,160,3] f32.
// R6: R4 structure (in-register weights — R5's tables regressed: chained
// loads on the serial window loop) with pass_z+pass_y FUSED into one
// LDS-staged kernel (block = (x, j-tile of 8); coeff rows + T1 tile in LDS),
// removing the T1 global round-trip and one launch. pass_x = R4 verbatim.

#define CX 80
#define FD 160
#define NY 12   // max y-rows per j-tile: stride<=1 -> floor spans <=7 over 8 j's -> 11 taps

__device__ inline void inv4(const float* m, float* inv) {
    inv[0]  =  m[5]*m[10]*m[15] - m[5]*m[11]*m[14] - m[9]*m[6]*m[15] + m[9]*m[7]*m[14] + m[13]*m[6]*m[11] - m[13]*m[7]*m[10];
    inv[4]  = -m[4]*m[10]*m[15] + m[4]*m[11]*m[14] + m[8]*m[6]*m[15] - m[8]*m[7]*m[14] - m[12]*m[6]*m[11] + m[12]*m[7]*m[10];
    inv[8]  =  m[4]*m[9]*m[15]  - m[4]*m[11]*m[13] - m[8]*m[5]*m[15] + m[8]*m[7]*m[13] + m[12]*m[5]*m[11] - m[12]*m[7]*m[9];
    inv[12] = -m[4]*m[9]*m[14]  + m[4]*m[10]*m[13] + m[8]*m[5]*m[14] - m[8]*m[6]*m[13] - m[12]*m[5]*m[10] + m[12]*m[6]*m[9];
    inv[1]  = -m[1]*m[10]*m[15] + m[1]*m[11]*m[14] + m[9]*m[2]*m[15] - m[9]*m[3]*m[14] - m[13]*m[2]*m[11] + m[13]*m[3]*m[10];
    inv[5]  =  m[0]*m[10]*m[15] - m[0]*m[11]*m[14] - m[8]*m[2]*m[15] + m[8]*m[3]*m[14] + m[12]*m[2]*m[11] - m[12]*m[3]*m[10];
    inv[9]  = -m[0]*m[9]*m[15]  + m[0]*m[11]*m[13] + m[8]*m[1]*m[15] - m[8]*m[3]*m[13] - m[12]*m[1]*m[11] + m[12]*m[3]*m[9];
    inv[13] =  m[0]*m[9]*m[14]  - m[0]*m[10]*m[13] - m[8]*m[1]*m[14] + m[8]*m[2]*m[13] + m[12]*m[1]*m[10] - m[12]*m[2]*m[9];
    inv[2]  =  m[1]*m[6]*m[15]  - m[1]*m[7]*m[14]  - m[5]*m[2]*m[15] + m[5]*m[3]*m[14] + m[13]*m[2]*m[7]  - m[13]*m[3]*m[6];
    inv[6]  = -m[0]*m[6]*m[15]  + m[0]*m[7]*m[14]  + m[4]*m[2]*m[15] - m[4]*m[3]*m[14] - m[12]*m[2]*m[7]  + m[12]*m[3]*m[6];
    inv[10] =  m[0]*m[5]*m[15]  - m[0]*m[7]*m[13]  - m[4]*m[1]*m[15] + m[4]*m[3]*m[13] + m[12]*m[1]*m[7]  - m[12]*m[3]*m[5];
    inv[14] = -m[0]*m[5]*m[14]  + m[0]*m[6]*m[13]  + m[4]*m[1]*m[14] - m[4]*m[2]*m[13] - m[12]*m[1]*m[6]  + m[12]*m[2]*m[5];
    inv[3]  = -m[1]*m[6]*m[11]  + m[1]*m[7]*m[10]  + m[5]*m[2]*m[11] - m[5]*m[3]*m[10] - m[9]*m[2]*m[7]   + m[9]*m[3]*m[6];
    inv[7]  =  m[0]*m[6]*m[11]  - m[0]*m[7]*m[10]  - m[4]*m[2]*m[11] + m[4]*m[3]*m[10] + m[8]*m[2]*m[7]   - m[8]*m[3]*m[6];
    inv[11] = -m[0]*m[5]*m[11]  + m[0]*m[7]*m[9]   + m[4]*m[1]*m[11] - m[4]*m[3]*m[9]  - m[8]*m[1]*m[7]   + m[8]*m[3]*m[5];
    inv[15] =  m[0]*m[5]*m[10]  - m[0]*m[6]*m[9]   - m[4]*m[1]*m[10] + m[4]*m[2]*m[9]  + m[8]*m[1]*m[6]   - m[8]*m[2]*m[5];
    float det = m[0]*inv[0] + m[1]*inv[4] + m[2]*inv[8] + m[3]*inv[12];
    float rdet = 1.0f / det;
    for (int i = 0; i < 16; ++i) inv[i] *= rdet;
}

// M[0..15]=fa, M[16..31]=ma, M[32]=separable flag (axis-aligned AND 0<diag<=1)
__global__ void setup_mats(const float* __restrict__ affine,
                           const float* __restrict__ fix_aff,
                           const float* __restrict__ mov_aff,
                           float* __restrict__ M) {
    if (threadIdx.x != 0 || blockIdx.x != 0) return;
    float invA[16], invM[16];
    inv4(affine, invA);
    inv4(mov_aff, invM);
    for (int r = 0; r < 4; ++r)
        for (int c = 0; c < 4; ++c) {
            float s = 0.f;
            for (int k = 0; k < 4; ++k) s += invA[r*4+k] * fix_aff[k*4+c];
            M[r*4+c] = s;
        }
    for (int r = 0; r < 4; ++r)
        for (int c = 0; c < 4; ++c) {
            float s = 0.f;
            for (int k = 0; k < 4; ++k) s += invM[r*4+k] * affine[k*4+c];
            M[16 + r*4+c] = s;
        }
    float od = fabsf(M[1]) + fabsf(M[2]) + fabsf(M[4]) + fabsf(M[6]) + fabsf(M[8]) + fabsf(M[9]);
    int ok = (od < 1e-20f)
          && (M[0]  > 0.f) && (M[0]  <= 1.f)
          && (M[5]  > 0.f) && (M[5]  <= 1.f)
          && (M[10] > 0.f) && (M[10] <= 1.f);
    M[32] = ok ? 1.f : 0.f;
}

__device__ inline void bspline_w(float t, float w[4]) {
    float t2 = t * t;
    float t3 = t2 * t;
    const float s = 1.0f / 6.0f;
    w[0] = (1.f - 3.f*t + 3.f*t2 - t3) * s;
    w[1] = (4.f - 6.f*t2 + 3.f*t3) * s;
    w[2] = (1.f + 3.f*t + 3.f*t2 - 3.f*t3) * s;
    w[3] = t3 * s;
}

__device__ inline int wrap80(int v) {
    int r = v % CX;
    return (r < 0) ? r + CX : r;
}

// Fused z+y: block = (x, j-tile of 8). Stage NY coeff y-rows in LDS,
// z-interp to an LDS T1-tile, y-interp, write T2 coalesced along k.
// Grid: 80 * 20 = 1600 blocks.
__global__ __launch_bounds__(256) void fused_zy(const float* __restrict__ coeff,
                                                const float* __restrict__ M,
                                                float4* __restrict__ T2) {
    if (M[32] == 0.f) return;
    __shared__ float  sc[NY * CX * 3];     // 12*240 floats = 11.5 KB
    __shared__ float4 st1[NY * FD];        // 12*160 float4 = 30.7 KB

    int x  = blockIdx.x / 20;
    int jt = blockIdx.x % 20;
    int j0 = jt * 8;

    const float m5 = M[5], m7 = M[7], m10 = M[10], m11 = M[11];
    int by0 = (int)floorf(m5 * (float)j0 + m7) - 1;

    // stage coeff rows (wrapped y window), coalesced within rows
    const float* cx = coeff + (size_t)x * (CX * CX * 3);
    for (int idx = threadIdx.x; idx < NY * CX * 3; idx += 256) {
        int row = idx / (CX * 3);
        int e   = idx % (CX * 3);
        sc[idx] = cx[(size_t)wrap80(by0 + row) * (CX * 3) + e];
    }
    __syncthreads();

    // phase 1: z-interp each staged row at all 160 k's
    for (int item = threadIdx.x; item < NY * FD; item += 256) {
        int yl = item / FD;
        int k  = item % FD;
        float gz = m10 * (float)k + m11;
        float fz = floorf(gz);
        float wz[4];
        bspline_w(gz - fz, wz);
        int bz = (int)fz - 1;
        int z0 = wrap80(bz);
        int z1 = z0 + 1; if (z1 >= CX) z1 -= CX;
        int z2 = z1 + 1; if (z2 >= CX) z2 -= CX;
        int z3 = z2 + 1; if (z3 >= CX) z3 -= CX;
        const float* row = sc + yl * (CX * 3);
        float4 v;
        v.x = wz[0]*row[z0*3+0] + wz[1]*row[z1*3+0] + wz[2]*row[z2*3+0] + wz[3]*row[z3*3+0];
        v.y = wz[0]*row[z0*3+1] + wz[1]*row[z1*3+1] + wz[2]*row[z2*3+1] + wz[3]*row[z3*3+1];
        v.z = wz[0]*row[z0*3+2] + wz[1]*row[z1*3+2] + wz[2]*row[z2*3+2] + wz[3]*row[z3*3+2];
        v.w = 0.f;
        st1[item] = v;
    }
    __syncthreads();

    // phase 2: y-interp the tile's 8 j's, write T2[x][j][k]
    for (int item = threadIdx.x; item < 8 * FD; item += 256) {
        int jl = item / FD;
        int k  = item % FD;
        int j  = j0 + jl;
        float gy = m5 * (float)j + m7;
        float fy = floorf(gy);
        float wy[4];
        bspline_w(gy - fy, wy);
        int row = ((int)fy - 1) - by0;          // in [0, NY-4]
        const float4* p = st1 + row * FD + k;
        float4 w0 = p[0], w1 = p[FD], w2 = p[2*FD], w3 = p[3*FD];
        float4 v;
        v.x = wy[0]*w0.x + wy[1]*w1.x + wy[2]*w2.x + wy[3]*w3.x;
        v.y = wy[0]*w0.y + wy[1]*w1.y + wy[2]*w2.y + wy[3]*w3.y;
        v.z = wy[0]*w0.z + wy[1]*w1.z + wy[2]*w2.z + wy[3]*w3.z;
        v.w = 0.f;
        T2[((size_t)(x * FD + j)) * FD + k] = v;
    }
}

// Pass 3: x-interp + displacement + ma affine, coarsened 8 i's/thread (R4 verbatim).
// 20*160*160 = 512,000 threads.
__global__ __launch_bounds__(256) void pass_x_c(const float* __restrict__ coeff,
                                                const float* __restrict__ M,
                                                const float4* __restrict__ T2,
                                                float* __restrict__ out) {
    int tid = blockIdx.x * 256 + threadIdx.x;
    int k = tid % FD;
    int r = tid / FD;
    int j = r % FD;
    int ig = r / FD;
    int i0 = ig * 8;

    if (M[32] != 0.f) {
        const float m0 = M[0], m3 = M[3];
        const float gy = M[5] * (float)j + M[7];
        const float gz = M[10] * (float)k + M[11];
        const float4* Tjk = T2 + (size_t)j * FD + k;

        float gx = m0 * (float)i0 + m3;
        float fx = floorf(gx);
        int nb = (int)fx - 1;
        float wx[4];
        bspline_w(gx - fx, wx);

        float4 w0, w1, w2, w3;
        {
            int x0 = wrap80(nb);
            int x1 = x0 + 1; if (x1 >= CX) x1 -= CX;
            int x2 = x1 + 1; if (x2 >= CX) x2 -= CX;
            int x3 = x2 + 1; if (x3 >= CX) x3 -= CX;
            w0 = Tjk[(size_t)x0 * FD * FD];
            w1 = Tjk[(size_t)x1 * FD * FD];
            w2 = Tjk[(size_t)x2 * FD * FD];
            w3 = Tjk[(size_t)x3 * FD * FD];
        }

        float* po = out + (((size_t)(i0 * FD + j)) * FD + k) * 3;
#pragma unroll
        for (int d = 0; d < 8; ++d) {
            float gxd = gx;
            if (d > 0) {
                int i = i0 + d;
                gxd = m0 * (float)i + m3;
                float fx2 = floorf(gxd);
                int b2 = (int)fx2 - 1;
                if (b2 != nb) {
                    w0 = w1; w1 = w2; w2 = w3;
                    w3 = Tjk[(size_t)wrap80(b2 + 3) * FD * FD];
                    nb = b2;
                }
                bspline_w(gxd - fx2, wx);
            }
            float a0 = wx[0]*w0.x + wx[1]*w1.x + wx[2]*w2.x + wx[3]*w3.x;
            float a1 = wx[0]*w0.y + wx[1]*w1.y + wx[2]*w2.y + wx[3]*w3.y;
            float a2 = wx[0]*w0.z + wx[1]*w1.z + wx[2]*w2.z + wx[3]*w3.z;
            float ux = gxd + a0, uy = gy + a1, uz = gz + a2;
            po[0] = M[16]*ux + M[17]*uy + M[18]*uz + M[19];
            po[1] = M[20]*ux + M[21]*uy + M[22]*uz + M[23];
            po[2] = M[24]*ux + M[25]*uy + M[26]*uz + M[27];
            po += (size_t)FD * FD * 3;   // advance i by 1
        }
    } else {
        // non-separable fallback: direct 64-tap per output
        for (int d = 0; d < 8; ++d) {
            int i = i0 + d;
            float fi = (float)i, fj = (float)j, fk = (float)k;
            float gx = M[0]*fi + M[1]*fj + M[2]*fk  + M[3];
            float gy = M[4]*fi + M[5]*fj + M[6]*fk  + M[7];
            float gz = M[8]*fi + M[9]*fj + M[10]*fk + M[11];
            float fx = floorf(gx), fy = floorf(gy), fz = floorf(gz);
            float wx[4], wy[4], wz[4];
            bspline_w(gx - fx, wx);
            bspline_w(gy - fy, wy);
            bspline_w(gz - fz, wz);
            int bxw = wrap80((int)fx - 1);
            int byw = wrap80((int)fy - 1);
            int bzw = wrap80((int)fz - 1);
            int ox[4], oy[4], oz[4];
            for (int a = 0; a < 4; ++a) {
                int xa = bxw + a; if (xa >= CX) xa -= CX;
                int ya = byw + a; if (ya >= CX) ya -= CX;
                int za = bzw + a; if (za >= CX) za -= CX;
                ox[a] = xa * (CX*CX*3);
                oy[a] = ya * (CX*3);
                oz[a] = za * 3;
            }
            float a0 = 0.f, a1 = 0.f, a2 = 0.f;
            for (int a = 0; a < 4; ++a)
                for (int b = 0; b < 4; ++b)
                    for (int c = 0; c < 4; ++c) {
                        float w = wx[a] * wy[b] * wz[c];
                        const float* p = coeff + (ox[a] + oy[b] + oz[c]);
                        a0 = fmaf(w, p[0], a0);
                        a1 = fmaf(w, p[1], a1);
                        a2 = fmaf(w, p[2], a2);
                    }
            float ux = gx + a0, uy = gy + a1, uz = gz + a2;
            size_t o = ((size_t)(i * FD + j) * FD + k) * 3;
            out[o + 0] = M[16]*ux + M[17]*uy + M[18]*uz + M[19];
            out[o + 1] = M[20]*ux + M[21]*uy + M[22]*uz + M[23];
            out[o + 2] = M[24]*ux + M[25]*uy + M[26]*uz + M[27];
        }
    }
}

// Direct path used when ws can't hold intermediates.
__global__ __launch_bounds__(256) void spline_direct(const float* __restrict__ coeff,
                                                     const float* __restrict__ M,
                                                     float* __restrict__ out) {
    int tid = blockIdx.x * 256 + threadIdx.x;
    int k = tid % FD;
    int r = tid / FD;
    int j = r % FD;
    int i = r / FD;
    float fi = (float)i, fj = (float)j, fk = (float)k;
    float gx = M[0]*fi + M[1]*fj + M[2]*fk  + M[3];
    float gy = M[4]*fi + M[5]*fj + M[6]*fk  + M[7];
    float gz = M[8]*fi + M[9]*fj + M[10]*fk + M[11];
    float fx = floorf(gx), fy = floorf(gy), fz = floorf(gz);
    float wx[4], wy[4], wz[4];
    bspline_w(gx - fx, wx);
    bspline_w(gy - fy, wy);
    bspline_w(gz - fz, wz);
    int bxw = wrap80((int)fx - 1);
    int byw = wrap80((int)fy - 1);
    int bzw = wrap80((int)fz - 1);
    int ox[4], oy[4], oz[4];
#pragma unroll
    for (int a = 0; a < 4; ++a) {
        int xa = bxw + a; if (xa >= CX) xa -= CX;
        int ya = byw + a; if (ya >= CX) ya -= CX;
        int za = bzw + a; if (za >= CX) za -= CX;
        ox[a] = xa * (CX*CX*3);
        oy[a] = ya * (CX*3);
        oz[a] = za * 3;
    }
    float a0 = 0.f, a1 = 0.f, a2 = 0.f;
#pragma unroll
    for (int a = 0; a < 4; ++a)
#pragma unroll
        for (int b = 0; b < 4; ++b)
#pragma unroll
            for (int c = 0; c < 4; ++c) {
                float w = wx[a] * wy[b] * wz[c];
                const float* p = coeff + (ox[a] + oy[b] + oz[c]);
                a0 = fmaf(w, p[0], a0);
                a1 = fmaf(w, p[1], a1);
                a2 = fmaf(w, p[2], a2);
            }
    float ux = gx + a0, uy = gy + a1, uz = gz + a2;
    out[tid*3 + 0] = M[16]*ux + M[17]*uy + M[18]*uz + M[19];
    out[tid*3 + 1] = M[20]*ux + M[21]*uy + M[22]*uz + M[23];
    out[tid*3 + 2] = M[24]*ux + M[25]*uy + M[26]*uz + M[27];
}

extern "C" void kernel_launch(void* const* d_in, const int* in_sizes, int n_in,
                              void* d_out, int out_size, void* d_ws, size_t ws_size,
                              hipStream_t stream) {
    const float* coeff   = (const float*)d_in[0];
    const float* affine  = (const float*)d_in[1];
    const float* fix_aff = (const float*)d_in[2];
    const float* mov_aff = (const float*)d_in[3];
    float* M   = (float*)d_ws;                       // 64 floats
    char*  ws  = (char*)d_ws;
    float4* T2 = (float4*)(ws + 256);                // 80*160*160*16 = 32,768,000 B
    float* out = (float*)d_out;

    const size_t need = 256 + (size_t)CX*FD*FD*16;

    setup_mats<<<1, 64, 0, stream>>>(affine, fix_aff, mov_aff, M);

    if (ws_size >= need) {
        fused_zy<<<CX*20, 256, 0, stream>>>(coeff, M, T2);
        pass_x_c<<<(20*FD*FD)/256, 256, 0, stream>>>(coeff, M, T2, out);
    } else {
        spline_direct<<<(FD*FD*FD)/256, 256, 0, stream>>>(coeff, M, out);
    }
}